// Round 7
// baseline (540.731 us; speedup 1.0000x reference)
//
#include <hip/hip_runtime.h>
#include <hip/hip_bf16.h>

#define B_   2048
#define L_   64
#define H_   20
#define DK_  20
#define D_   300
#define HD_  400
#define F1_  200

typedef __attribute__((ext_vector_type(8))) short short8;
typedef __attribute__((ext_vector_type(4))) float f32x4;

// ---- workspace layout (kept EXACTLY at the R5/R6-proven requirement) ----
// [0, 819200)          : wqkv tiles, 800 * 1024 B
// [819200, 985600)     : W1 compact tiles: 130 * (512+128)*2 B  (kt0 full, kt1 compact)
// [1048576, +100 MB)   : ctx (bf16, row-major [b*64+tok][400])
// alpha-logits live in d_out (first 64 floats of each 400-row), no ws needed.
#define WQKV_TILES   800             // hg(10) * kt(10) * nt(8)
#define W1C_OFF_U16  409600          // after 800 wqkv tiles * 512 us
#define W1_KT0_FR    130             // hg(10) * nt(13)
#define CTX_OFF_B    1048576
#define CTX_BYTES    (2048L * 64 * 400 * 2)
#define WS_FULL      (CTX_OFF_B + CTX_BYTES)   // == 105906176, proven available

__device__ __forceinline__ float b2f(unsigned short u) {
    union { unsigned int i; float f; } v; v.i = ((unsigned int)u) << 16; return v.f;
}
__device__ __forceinline__ unsigned int f2b2(float a, float b) {
    union { __hip_bfloat162 h; unsigned int u; } cv;
    cv.h = __float22bfloat162_rn(make_float2(a, b));
    return cv.u;
}
__device__ __forceinline__ unsigned short f2b(float a) {
    union { __hip_bfloat16 h; unsigned short u; } cv;
    cv.h = __float2bfloat16(a);
    return cv.u;
}
__device__ __forceinline__ float rcpf(float x) { return __builtin_amdgcn_rcpf(x); }
__device__ __forceinline__ float rlane(float v, int l) {
    return __int_as_float(__builtin_amdgcn_readlane(__float_as_int(v), l));
}

// ==================== weight pre-pack v2 ====================
// frag < 800   : wqkv  (hg*80 + kt*8 + nt), per-hg cols [q40|k40|v40|pad8]
// 800..929     : W1 kt0 tiles (k_local 0..31), full 512 us at (hg*13+nt)*640
// 930..1059    : W1 kt1 compact (k_local 32..39), 128 us at (hg*13+nt)*640+512
__global__ void pack_weights_v2(const float* __restrict__ WQ, const float* __restrict__ WK,
                                const float* __restrict__ WV, const float* __restrict__ W1,
                                unsigned short* __restrict__ wsp)
{
    const int tid  = blockIdx.x * 256 + threadIdx.x;
    const int frag = tid >> 6, l = tid & 63;
    if (frag >= 1060) return;
    const int octet = l >> 4, lo = l & 15;
    if (frag < WQKV_TILES) {
        const int hg = frag / 80, r = frag % 80, kt = r / 8, nt = r % 8;
        const int nl = nt * 16 + lo;                  // [0,128)
        const int sel = (nl < 120) ? nl / 40 : 0;
        const int within = nl % 40;
        const int h2 = within / 20, d = within % 20;
        const int col = (hg * 2 + h2) * 20 + d;
        const float* W = (sel == 0) ? WQ : (sel == 1) ? WK : WV;
        unsigned short v[8];
        #pragma unroll
        for (int j = 0; j < 8; ++j) {
            const int k = kt * 32 + octet * 8 + j;
            const float f = (nl < 120 && k < 300) ? W[k * 400 + col] : 0.f;
            v[j] = f2b(f);
        }
        unsigned short* dst = wsp + (long)frag * 512 + l * 8;
        *(ushort4*)(dst)     = make_ushort4(v[0], v[1], v[2], v[3]);
        *(ushort4*)(dst + 4) = make_ushort4(v[4], v[5], v[6], v[7]);
    } else if (frag < 800 + W1_KT0_FR) {
        const int f2 = frag - 800, hg = f2 / 13, nt = f2 % 13;
        const int n = nt * 16 + lo;
        unsigned short v[8];
        #pragma unroll
        for (int j = 0; j < 8; ++j) {
            const int kl = octet * 8 + j;             // 0..31 < 40 always valid
            const float f = (n < 200) ? W1[(hg * 40 + kl) * 200 + n] : 0.f;
            v[j] = f2b(f);
        }
        unsigned short* dst = wsp + W1C_OFF_U16 + (long)(hg * 13 + nt) * 640 + l * 8;
        *(ushort4*)(dst)     = make_ushort4(v[0], v[1], v[2], v[3]);
        *(ushort4*)(dst + 4) = make_ushort4(v[4], v[5], v[6], v[7]);
    } else {
        const int f2 = frag - 800 - W1_KT0_FR, hg = f2 / 13, nt = f2 % 13;
        if (l < 16) {                                 // compact kt1: octet-0 lanes only
            const int n = nt * 16 + l;
            unsigned short v[8];
            #pragma unroll
            for (int j = 0; j < 8; ++j) {
                const float f = (n < 200) ? W1[(hg * 40 + 32 + j) * 200 + n] : 0.f;
                v[j] = f2b(f);
            }
            unsigned short* dst = wsp + W1C_OFF_U16 + (long)(hg * 13 + nt) * 640 + 512 + l * 8;
            *(ushort4*)(dst)     = make_ushort4(v[0], v[1], v[2], v[3]);
            *(ushort4*)(dst + 4) = make_ushort4(v[4], v[5], v[6], v[7]);
        }
    }
}

// ==================== te_attn helpers ====================
template<int S>
__device__ __forceinline__ void a_step(int hg0, int w, int l, bool act, int selbase,
                                       const unsigned short* xp,
                                       const unsigned short* __restrict__ wsp,
                                       const float* bq, f32x4 slab[][4])
{
    #pragma unroll
    for (int s = 0; s < S; ++s) {
        const float bv = act ? bq[selbase + (hg0 + s) * 40] : 0.f;
        #pragma unroll
        for (int mt = 0; mt < 4; ++mt) slab[s][mt] = (f32x4){bv, bv, bv, bv};
    }
    for (int kt = 0; kt < 10; ++kt) {
        short8 a[4];
        #pragma unroll
        for (int mt = 0; mt < 4; ++mt)
            a[mt] = *(const short8*)(xp + ((mt * 10 + kt) * 64 + l) * 8);
        #pragma unroll
        for (int s = 0; s < S; ++s) {
            const short8 bf = *(const short8*)(wsp + ((long)((hg0 + s) * 80 + kt * 8 + w) * 512) + l * 8);
            #pragma unroll
            for (int mt = 0; mt < 4; ++mt)
                slab[s][mt] = __builtin_amdgcn_mfma_f32_16x16x32_bf16(a[mt], bf, slab[s][mt], 0, 0, 0);
        }
    }
}

// incremental pooling-GEMM accumulation over one hg's ctx slice (stage, row-major [tok][40])
__device__ __forceinline__ void d_accum(int hg, int l, int w, int quad,
                                        const unsigned short* stage,
                                        const unsigned short* __restrict__ wsp,
                                        f32x4 accD[2][4])
{
    short8 a0[4], a1[4];
    const short8 zz = {0, 0, 0, 0, 0, 0, 0, 0};
    #pragma unroll
    for (int mt = 0; mt < 4; ++mt) {
        const int tok = mt * 16 + (l & 15);
        a0[mt] = *(const short8*)(stage + tok * 40 + quad * 8);
        a1[mt] = (quad == 0) ? *(const short8*)(stage + tok * 40 + 32) : zz;
    }
    const int nta = w, ntb = w + 8;
    {
        const unsigned short* base = wsp + W1C_OFF_U16 + (long)(hg * 13 + nta) * 640;
        const short8 wb0 = *(const short8*)(base + l * 8);
        const short8 wb1 = *(const short8*)(base + 512 + (l & 15) * 8);   // octet-bcast; A zeros cover
        #pragma unroll
        for (int mt = 0; mt < 4; ++mt) {
            accD[0][mt] = __builtin_amdgcn_mfma_f32_16x16x32_bf16(a0[mt], wb0, accD[0][mt], 0, 0, 0);
            accD[0][mt] = __builtin_amdgcn_mfma_f32_16x16x32_bf16(a1[mt], wb1, accD[0][mt], 0, 0, 0);
        }
    }
    if (ntb < 13) {
        const unsigned short* base = wsp + W1C_OFF_U16 + (long)(hg * 13 + ntb) * 640;
        const short8 wb0 = *(const short8*)(base + l * 8);
        const short8 wb1 = *(const short8*)(base + 512 + (l & 15) * 8);
        #pragma unroll
        for (int mt = 0; mt < 4; ++mt) {
            accD[1][mt] = __builtin_amdgcn_mfma_f32_16x16x32_bf16(a0[mt], wb0, accD[1][mt], 0, 0, 0);
            accD[1][mt] = __builtin_amdgcn_mfma_f32_16x16x32_bf16(a1[mt], wb1, accD[1][mt], 0, 0, 0);
        }
    }
}

// per-head-group attention body (5 barriers); also drains prev hg's ctx (copy + D-accum)
__device__ __forceinline__ void attn_hg_body(
    int hg, const f32x4* sl, int b, int t, int l, int w,
    bool act, int sel, int baseQK, int baseV, int quad,
    unsigned short* trans, unsigned short* vBs, unsigned short* stage,
    float* rsum_s, unsigned short* __restrict__ ctx_ws,
    const unsigned short* __restrict__ wsp, f32x4 accD[2][4])
{
    if (hg > 0) {
        for (int u = t; u < 640; u += 512) {
            const int row = u / 10, c4 = u - row * 10;
            const ushort4 v = *(const ushort4*)(stage + row * 40 + c4 * 4);
            *(ushort4*)(ctx_ws + ((long)(b * 64 + row)) * 400 + (hg - 1) * 40 + c4 * 4) = v;
        }
        d_accum(hg - 1, l, w, quad, stage, wsp, accD);
    }
    // scatter this hg's QKV slab into qA/kB/vB layouts
    if (act) {
        const unsigned int u01a = f2b2(sl[0][0], sl[0][1]), u23a = f2b2(sl[0][2], sl[0][3]);
        const unsigned int u01b = f2b2(sl[1][0], sl[1][1]), u23b = f2b2(sl[1][2], sl[1][3]);
        const unsigned int u01c = f2b2(sl[2][0], sl[2][1]), u23c = f2b2(sl[2][2], sl[2][3]);
        const unsigned int u01d = f2b2(sl[3][0], sl[3][1]), u23d = f2b2(sl[3][2], sl[3][3]);
        const unsigned int p01[4] = {u01a, u01b, u01c, u01d};
        const unsigned int p23[4] = {u23a, u23b, u23c, u23d};
        if (sel < 2) {
            #pragma unroll
            for (int mt = 0; mt < 4; ++mt) {
                const int a0 = baseQK + mt * 512;
                trans[a0]      = (unsigned short)p01[mt];
                trans[a0 + 8]  = (unsigned short)(p01[mt] >> 16);
                trans[a0 + 16] = (unsigned short)p23[mt];
                trans[a0 + 24] = (unsigned short)(p23[mt] >> 16);
            }
        } else {
            #pragma unroll
            for (int mt = 0; mt < 4; ++mt) {
                const int bm = baseV + (mt >> 1) * 1024 + (mt & 1) * 256;
                #pragma unroll
                for (int ii = 0; ii < 4; ++ii) {
                    const int tq = quad * 4 + ii;
                    const unsigned int uu = (ii < 2) ? p01[mt] : p23[mt];
                    vBs[bm + (tq >> 3) * 128 + (tq & 7)] =
                        (unsigned short)((ii & 1) ? (uu >> 16) : uu);
                }
            }
        }
    }
    __syncthreads();                                   // B1

    // Phase B: S = Q@K^T, exp -> pA (overlays qA/kB)
    const int h = w >> 2, jt = w & 3;
    f32x4 accS[4];
    #pragma unroll
    for (int mt = 0; mt < 4; ++mt) accS[mt] = (f32x4){0.f, 0.f, 0.f, 0.f};
    {
        short8 qa[4];
        #pragma unroll
        for (int mt = 0; mt < 4; ++mt)
            qa[mt] = *(const short8*)(trans + ((h * 4 + mt) * 64 + l) * 8);
        const short8 kb = *(const short8*)(trans + 4096 + ((h * 4 + jt) * 64 + l) * 8);
        #pragma unroll
        for (int mt = 0; mt < 4; ++mt)
            accS[mt] = __builtin_amdgcn_mfma_f32_16x16x32_bf16(qa[mt], kb, accS[mt], 0, 0, 0);
    }
    __syncthreads();                                   // B2
    {
        const int jtok = jt * 16 + (l & 15);
        const int ktp = jtok >> 5;
        #pragma unroll
        for (int mt = 0; mt < 4; ++mt) {
            const float e0 = __expf(accS[mt][0] * 0.22360679774997896f);
            const float e1 = __expf(accS[mt][1] * 0.22360679774997896f);
            const float e2 = __expf(accS[mt][2] * 0.22360679774997896f);
            const float e3 = __expf(accS[mt][3] * 0.22360679774997896f);
            const unsigned int u01 = f2b2(e0, e1), u23 = f2b2(e2, e3);
            const int a0 = (((h * 4 + mt) * 2 + ktp) * 64 + quad * 4 + ((jtok & 31) >> 3) * 16) * 8 + (jtok & 7);
            trans[a0]      = (unsigned short)u01;
            trans[a0 + 8]  = (unsigned short)(u01 >> 16);
            trans[a0 + 16] = (unsigned short)u23;
            trans[a0 + 24] = (unsigned short)(u23 >> 16);
        }
    }
    __syncthreads();                                   // B3

    // Phase C: PV (+rowsum via ones col)
    const int dnt = (w >> 1) & 1, mh = w & 1;
    f32x4 accC[2];
    accC[0] = (f32x4){0.f, 0.f, 0.f, 0.f};
    accC[1] = (f32x4){0.f, 0.f, 0.f, 0.f};
    #pragma unroll
    for (int ktc = 0; ktc < 2; ++ktc) {
        const short8 vb = *(const short8*)(vBs + (((h * 2 + ktc) * 2 + dnt) * 64 + l) * 8);
        #pragma unroll
        for (int mi = 0; mi < 2; ++mi) {
            const int mt = mh * 2 + mi;
            const short8 pa = *(const short8*)(trans + (((h * 4 + mt) * 2 + ktc) * 64 + l) * 8);
            accC[mi] = __builtin_amdgcn_mfma_f32_16x16x32_bf16(pa, vb, accC[mi], 0, 0, 0);
        }
    }
    if (dnt == 1 && (l & 15) == 4) {
        #pragma unroll
        for (int mi = 0; mi < 2; ++mi)
            #pragma unroll
            for (int ii = 0; ii < 4; ++ii)
                rsum_s[h * 64 + (mh * 2 + mi) * 16 + quad * 4 + ii] = accC[mi][ii];
    }
    __syncthreads();                                   // B4
    if (hg < 9) {
        unsigned int* tz = (unsigned int*)trans;
        for (int i = t; i < 4096; i += 512) tz[i] = 0u;
    }
    {
        const int dloc = dnt * 16 + (l & 15);
        if (dloc < 20) {
            const int cl = h * 20 + dloc;
            #pragma unroll
            for (int mi = 0; mi < 2; ++mi) {
                const int mt = mh * 2 + mi;
                float vv[4];
                #pragma unroll
                for (int ii = 0; ii < 4; ++ii) {
                    const int tok = mt * 16 + quad * 4 + ii;
                    vv[ii] = accC[mi][ii] * rcpf(rsum_s[h * 64 + tok] + 1e-8f);
                }
                const unsigned int u01 = f2b2(vv[0], vv[1]), u23 = f2b2(vv[2], vv[3]);
                const int base = (mt * 16 + quad * 4) * 40 + cl;
                stage[base]       = (unsigned short)u01;
                stage[base + 40]  = (unsigned short)(u01 >> 16);
                stage[base + 80]  = (unsigned short)u23;
                stage[base + 120] = (unsigned short)(u23 >> 16);
            }
        }
    }
    __syncthreads();                                   // B5
}

// ==================== kernel 1: attention + fused pooling-GEMM ====================
__global__ __launch_bounds__(512, 4)
void te_attn(const int* __restrict__ text,
             const float* __restrict__ emb,
             const float* __restrict__ bQ, const float* __restrict__ bK,
             const float* __restrict__ bV,
             const float* __restrict__ b1, const float* __restrict__ W2,
             const unsigned short* __restrict__ wsp,
             unsigned short* __restrict__ ctx_ws,
             float* __restrict__ logit_out)       // = d_out; logits at [b*400 + tok]
{
    __shared__ unsigned short x_pack[4 * 10 * 64 * 8];   // 40960 B
    __shared__ unsigned short trans[8192];               // 16384 B
    __shared__ unsigned short vB[4096];                  // 8192 B
    __shared__ unsigned short ctx_stage[64 * 40];        // 5120 B
    __shared__ float bqkv_s[1200];
    __shared__ float b1_s[208], w2_s[208];
    __shared__ float rsum_s[128];
    __shared__ float aacc_s[64];
    __shared__ int   text_s[64];

    const int b = blockIdx.x;
    const int t = threadIdx.x;
    const int l = t & 63;
    const int w = t >> 6;
    const int quad = l >> 4;

    {
        unsigned int* xz = (unsigned int*)x_pack;
        for (int i = t; i < 10240; i += 512) xz[i] = 0u;
        unsigned int* tz = (unsigned int*)trans;
        for (int i = t; i < 4096; i += 512) tz[i] = 0u;
        unsigned int* vz = (unsigned int*)vB;
        for (int i = t; i < 2048; i += 512) {
            const int tile = i >> 8;
            const int lane_v = (i & 255) >> 2;
            vz[i] = ((tile & 1) == 1 && (lane_v & 15) == 4) ? 0x3F803F80u : 0u;
        }
        for (int i = t; i < 1200; i += 512)
            bqkv_s[i] = (i < 400) ? bQ[i] : (i < 800) ? bK[i - 400] : bV[i - 800];
        if (t < 208) { b1_s[t] = (t < 200) ? b1[t] : 0.f; w2_s[t] = (t < 200) ? W2[t] : 0.f; }
        if (t >= 208 && t < 272) aacc_s[t - 208] = 0.f;
        if (t >= 272 && t < 336) text_s[t - 272] = text[b * L_ + (t - 272)];
    }
    __syncthreads();

    for (int u = t; u < 64 * 75; u += 512) {
        const int r = u / 75, c4 = u - r * 75, k = c4 * 4;
        const float4 f = *(const float4*)(emb + (long)text_s[r] * D_ + k);
        const int mt = r >> 4, kt = k >> 5;
        const int ld = (r & 15) + ((k & 31) >> 3) * 16;
        const unsigned int u01 = f2b2(f.x, f.y), u23 = f2b2(f.z, f.w);
        *(uint2*)(x_pack + ((mt * 10 + kt) * 64 + ld) * 8 + (k & 7)) = make_uint2(u01, u23);
    }
    __syncthreads();

    const int nl = w * 16 + (l & 15);
    const bool act = nl < 120;
    int sel = 0, h2 = 0, d = 0;
    if (act) { sel = nl / 40; const int within = nl % 40; h2 = within / 20; d = within % 20; }
    const int baseQK = h2 * 2048 + (quad * 4 + (d >> 3) * 16) * 8 + (d & 7) + ((sel == 1) ? 4096 : 0);
    const int baseV  = h2 * 2048 + (d >> 4) * 512 + (d & 15) * 8;
    const int selbase = sel * 400 + h2 * 20 + d;

    f32x4 accD[2][4];
    #pragma unroll
    for (int g = 0; g < 2; ++g)
        #pragma unroll
        for (int mt = 0; mt < 4; ++mt) accD[g][mt] = (f32x4){0.f, 0.f, 0.f, 0.f};

    f32x4 slab[3][4];
    a_step<3>(0, w, l, act, selbase, x_pack, wsp, bqkv_s, slab);
    attn_hg_body(0, slab[0], b, t, l, w, act, sel, baseQK, baseV, quad, trans, vB, ctx_stage, rsum_s, ctx_ws, wsp, accD);
    attn_hg_body(1, slab[1], b, t, l, w, act, sel, baseQK, baseV, quad, trans, vB, ctx_stage, rsum_s, ctx_ws, wsp, accD);
    attn_hg_body(2, slab[2], b, t, l, w, act, sel, baseQK, baseV, quad, trans, vB, ctx_stage, rsum_s, ctx_ws, wsp, accD);
    a_step<3>(3, w, l, act, selbase, x_pack, wsp, bqkv_s, slab);
    attn_hg_body(3, slab[0], b, t, l, w, act, sel, baseQK, baseV, quad, trans, vB, ctx_stage, rsum_s, ctx_ws, wsp, accD);
    attn_hg_body(4, slab[1], b, t, l, w, act, sel, baseQK, baseV, quad, trans, vB, ctx_stage, rsum_s, ctx_ws, wsp, accD);
    attn_hg_body(5, slab[2], b, t, l, w, act, sel, baseQK, baseV, quad, trans, vB, ctx_stage, rsum_s, ctx_ws, wsp, accD);
    a_step<2>(6, w, l, act, selbase, x_pack, wsp, bqkv_s, slab);
    attn_hg_body(6, slab[0], b, t, l, w, act, sel, baseQK, baseV, quad, trans, vB, ctx_stage, rsum_s, ctx_ws, wsp, accD);
    attn_hg_body(7, slab[1], b, t, l, w, act, sel, baseQK, baseV, quad, trans, vB, ctx_stage, rsum_s, ctx_ws, wsp, accD);
    a_step<2>(8, w, l, act, selbase, x_pack, wsp, bqkv_s, slab);
    attn_hg_body(8, slab[0], b, t, l, w, act, sel, baseQK, baseV, quad, trans, vB, ctx_stage, rsum_s, ctx_ws, wsp, accD);
    attn_hg_body(9, slab[1], b, t, l, w, act, sel, baseQK, baseV, quad, trans, vB, ctx_stage, rsum_s, ctx_ws, wsp, accD);

    // tail: drain hg=9 (copy + D-accum), then logits
    for (int u = t; u < 640; u += 512) {
        const int row = u / 10, c4 = u - row * 10;
        const ushort4 v = *(const ushort4*)(ctx_stage + row * 40 + c4 * 4);
        *(ushort4*)(ctx_ws + ((long)(b * 64 + row)) * 400 + 9 * 40 + c4 * 4) = v;
    }
    d_accum(9, l, w, quad, ctx_stage, wsp, accD);

    // logit epilogue: tanh(e)+·W2, reduce over cols -> aacc_s[tok]
    #pragma unroll
    for (int g = 0; g < 2; ++g) {
        const int ntv = (g == 0) ? w : w + 8;
        if (ntv < 13) {
            const int colb = ntv * 16 + (l & 15);      // cols>=200 have b1=w2=0 -> contribute 0
            const float b1v = b1_s[colb], w2v = w2_s[colb];
            #pragma unroll
            for (int mt = 0; mt < 4; ++mt) {
                float part[4];
                #pragma unroll
                for (int ii = 0; ii < 4; ++ii) {
                    const float x = accD[g][mt][ii] + b1v;
                    const float ex = __expf(2.f * x);
                    part[ii] = (1.f - 2.f * rcpf(ex + 1.f)) * w2v;
                }
                #pragma unroll
                for (int ii = 0; ii < 4; ++ii) {
                    float v = part[ii];
                    v += __shfl_xor(v, 1, 64); v += __shfl_xor(v, 2, 64);
                    v += __shfl_xor(v, 4, 64); v += __shfl_xor(v, 8, 64);
                    if ((l & 15) == 0)
                        atomicAdd(&aacc_s[mt * 16 + quad * 4 + ii], v);
                }
            }
        }
    }
    __syncthreads();
    if (t < 64)
        logit_out[(long)b * HD_ + t] = aacc_s[t];
}

// ==================== kernel 2: output (alpha + weighted sum) ====================
__global__ __launch_bounds__(512, 4)
void te_out(const unsigned short* __restrict__ ctx_ws,
            const float* __restrict__ b2,
            float* __restrict__ out)            // rows hold logits in [0,64) on entry
{
    __shared__ unsigned short ctx_l[64 * 400];  // 51200 B
    __shared__ float alpha_s[64];

    const int b = blockIdx.x;
    const int t = threadIdx.x;

    float av = 0.f;
    if (t < 64) av = __expf(out[(long)b * HD_ + t] + b2[0]);   // read logits FIRST

    // stage ctx (coalesced 16B)
    for (int u = t; u < 3200; u += 512) {
        const int row = u / 50, c8 = u - row * 50;
        *(short8*)(ctx_l + row * 400 + c8 * 8) =
            *(const short8*)(ctx_ws + ((long)(b * 64 + row)) * 400 + c8 * 8);
    }
    if (t < 64) {
        float s = av;
        s += __shfl_xor(s, 32, 64); s += __shfl_xor(s, 16, 64);
        s += __shfl_xor(s, 8, 64);  s += __shfl_xor(s, 4, 64);
        s += __shfl_xor(s, 2, 64);  s += __shfl_xor(s, 1, 64);
        alpha_s[t] = av * rcpf(s + 1e-8f);
    }
    __syncthreads();

    if (t < HD_) {
        float a = 0.f;
        #pragma unroll 4
        for (int tok = 0; tok < 64; ++tok)
            a = fmaf(b2f(ctx_l[tok * 400 + t]), alpha_s[tok], a);
        out[(long)b * HD_ + t] = a;
    }
}

// ==================== last-resort fallback (no workspace) ====================
#define XS   324
#define CS   404
#define QS   21
#define SS   66

__global__ __launch_bounds__(512, 2)
void te_fused_fb(const int* __restrict__ text, const float* __restrict__ emb,
                 const float* __restrict__ WQ, const float* __restrict__ bQ,
                 const float* __restrict__ WK, const float* __restrict__ bK,
                 const float* __restrict__ WV, const float* __restrict__ bV,
                 const float* __restrict__ W1, const float* __restrict__ b1,
                 const float* __restrict__ W2, const float* __restrict__ b2,
                 float* __restrict__ out)
{
    __shared__ int            text_s[L_];
    __shared__ unsigned short x_s[L_ * XS];
    __shared__ unsigned short ctx_s[L_ * CS];
    __shared__ float          qkv_s[3 * 2 * L_ * QS];
    __shared__ unsigned short sc_s[2 * L_ * SS];
    __shared__ float          aacc_s[L_], alpha_s[L_];
    __shared__ float          inv_asum_s;

    const int b = blockIdx.x, t = threadIdx.x, lane = t & 63, wv = t >> 6;
    if (t < 64) text_s[t] = text[b * L_ + t];
    if (t >= 64 && t < 128) aacc_s[t - 64] = 0.f;
    __syncthreads();
    for (int u = t; u < L_ * 75; u += 512) {
        int l = u / 75, c4 = u - l * 75;
        const float4 f = *(const float4*)(emb + (long)text_s[l] * D_ + c4 * 4);
        ushort4 o; o.x = f2b(f.x); o.y = f2b(f.y); o.z = f2b(f.z); o.w = f2b(f.w);
        *(ushort4*)(x_s + l * XS + c4 * 4) = o;
    }
    __syncthreads();
    for (int hp = 0; hp < H_ / 2; ++hp) {
        const int h0 = hp * 2;
        if (t < 480) {
            const int rt = t & 15, ct = t >> 4, r0 = rt * 4, qc = ct * 4;
            const int sel = qc / 40, rem = qc - sel * 40, hh = rem / 20, cc = rem - hh * 20;
            const float* W = (sel == 0) ? WQ : (sel == 1) ? WK : WV;
            const float* bias = (sel == 0) ? bQ : (sel == 1) ? bK : bV;
            const int col0 = (h0 + hh) * 20 + cc;
            float acc[4][4];
            #pragma unroll
            for (int j = 0; j < 4; ++j) {
                const float bj = bias[col0 + j];
                acc[0][j] = bj; acc[1][j] = bj; acc[2][j] = bj; acc[3][j] = bj;
            }
            const float* Wp = W + col0;
            for (int c4 = 0; c4 < 75; ++c4) {
                const int d0 = c4 * 4;
                float xv[4][4]; float4 wvv[4];
                #pragma unroll
                for (int i = 0; i < 4; ++i) {
                    ushort4 xu = *(const ushort4*)(x_s + (r0 + i) * XS + d0);
                    xv[i][0] = b2f(xu.x); xv[i][1] = b2f(xu.y);
                    xv[i][2] = b2f(xu.z); xv[i][3] = b2f(xu.w);
                }
                #pragma unroll
                for (int dd = 0; dd < 4; ++dd)
                    wvv[dd] = *(const float4*)(Wp + (long)(d0 + dd) * HD_);
                #pragma unroll
                for (int dd = 0; dd < 4; ++dd)
                    #pragma unroll
                    for (int i = 0; i < 4; ++i) {
                        acc[i][0] = fmaf(xv[i][dd], wvv[dd].x, acc[i][0]);
                        acc[i][1] = fmaf(xv[i][dd], wvv[dd].y, acc[i][1]);
                        acc[i][2] = fmaf(xv[i][dd], wvv[dd].z, acc[i][2]);
                        acc[i][3] = fmaf(xv[i][dd], wvv[dd].w, acc[i][3]);
                    }
            }
            #pragma unroll
            for (int i = 0; i < 4; ++i)
                #pragma unroll
                for (int j = 0; j < 4; ++j)
                    qkv_s[((sel * 2 + hh) * L_ + r0 + i) * QS + cc + j] = acc[i][j];
        }
        __syncthreads();
        {
            const int j = lane, ig = wv & 3, hh = wv >> 2;
            float qreg[20], kreg[20];
            const float* qrow = &qkv_s[((0 * 2 + hh) * L_ + j) * QS];
            const float* krow = &qkv_s[((1 * 2 + hh) * L_ + j) * QS];
            #pragma unroll
            for (int dd = 0; dd < 20; ++dd) { qreg[dd] = qrow[dd]; kreg[dd] = krow[dd]; }
            for (int ii = 0; ii < 16; ++ii) {
                const int i = ig * 16 + ii;
                float s = 0.f;
                #pragma unroll
                for (int dd = 0; dd < 20; ++dd) s = fmaf(rlane(qreg[dd], i), kreg[dd], s);
                sc_s[(hh * L_ + i) * SS + j] = f2b(__expf(s * 0.22360679774997896f));
            }
        }
        __syncthreads();
        {
            const int i = lane, dg = wv, head = dg >> 2, dv0 = (dg & 3) * 5;
            float vreg[5];
            #pragma unroll
            for (int m = 0; m < 5; ++m)
                vreg[m] = qkv_s[((2 * 2 + head) * L_ + i) * QS + dv0 + m];
            float acc[5] = {0.f, 0.f, 0.f, 0.f, 0.f};
            float rsum = 0.f;
            const unsigned short* prow = &sc_s[(head * L_ + i) * SS];
            for (int jj = 0; jj < 64; ++jj) {
                const float p = b2f(prow[jj]);
                rsum += p;
                #pragma unroll
                for (int m = 0; m < 5; ++m) acc[m] = fmaf(p, rlane(vreg[m], jj), acc[m]);
            }
            const float inv = 1.f / (rsum + 1e-8f);
            const int col0 = (h0 + head) * 20 + dv0;
            #pragma unroll
            for (int m = 0; m < 5; ++m) ctx_s[i * CS + col0 + m] = f2b(acc[m] * inv);
        }
        __syncthreads();
    }
    for (int tau = t; tau < 800; tau += 512) {
        const int rt = tau & 15, cm = tau >> 4, r0 = rt * 4, m0 = cm * 4;
        float acc[4][4];
        #pragma unroll
        for (int j = 0; j < 4; ++j) {
            const float bj = b1[m0 + j];
            acc[0][j] = bj; acc[1][j] = bj; acc[2][j] = bj; acc[3][j] = bj;
        }
        for (int c4 = 0; c4 < 100; ++c4) {
            const int c0 = c4 * 4;
            float cv[4][4]; float4 wv1[4];
            #pragma unroll
            for (int i = 0; i < 4; ++i) {
                ushort4 cu = *(const ushort4*)(ctx_s + (r0 + i) * CS + c0);
                cv[i][0] = b2f(cu.x); cv[i][1] = b2f(cu.y);
                cv[i][2] = b2f(cu.z); cv[i][3] = b2f(cu.w);
            }
            #pragma unroll
            for (int dd = 0; dd < 4; ++dd)
                wv1[dd] = *(const float4*)(W1 + (long)(c0 + dd) * F1_ + m0);
            #pragma unroll
            for (int dd = 0; dd < 4; ++dd)
                #pragma unroll
                for (int i = 0; i < 4; ++i) {
                    acc[i][0] = fmaf(cv[i][dd], wv1[dd].x, acc[i][0]);
                    acc[i][1] = fmaf(cv[i][dd], wv1[dd].y, acc[i][1]);
                    acc[i][2] = fmaf(cv[i][dd], wv1[dd].z, acc[i][2]);
                    acc[i][3] = fmaf(cv[i][dd], wv1[dd].w, acc[i][3]);
                }
        }
        float w2l[4];
        #pragma unroll
        for (int j = 0; j < 4; ++j) w2l[j] = W2[m0 + j];
        #pragma unroll
        for (int i = 0; i < 4; ++i) {
            float ap = 0.f;
            #pragma unroll
            for (int j = 0; j < 4; ++j) ap += tanhf(acc[i][j]) * w2l[j];
            atomicAdd(&aacc_s[r0 + i], ap);
        }
    }
    __syncthreads();
    if (t < 64) {
        const float a = __expf(aacc_s[t] + b2[0]);
        alpha_s[t] = a;
        float s = a;
        s += __shfl_xor(s, 32, 64); s += __shfl_xor(s, 16, 64);
        s += __shfl_xor(s, 8, 64);  s += __shfl_xor(s, 4, 64);
        s += __shfl_xor(s, 2, 64);  s += __shfl_xor(s, 1, 64);
        if (t == 0) inv_asum_s = 1.f / (s + 1e-8f);
    }
    __syncthreads();
    if (t < HD_) {
        float a = 0.f;
        for (int l2 = 0; l2 < 64; ++l2)
            a = fmaf(b2f(ctx_s[l2 * CS + t]), alpha_s[l2], a);
        out[(long)b * HD_ + t] = a * inv_asum_s;
    }
}

extern "C" void kernel_launch(void* const* d_in, const int* in_sizes, int n_in,
                              void* d_out, int out_size, void* d_ws, size_t ws_size,
                              hipStream_t stream) {
    const int*   text = (const int*)d_in[0];
    const float* emb  = (const float*)d_in[1];
    const float* WQ   = (const float*)d_in[2];
    const float* bQ   = (const float*)d_in[3];
    const float* WK   = (const float*)d_in[4];
    const float* bK   = (const float*)d_in[5];
    const float* WV   = (const float*)d_in[6];
    const float* bV   = (const float*)d_in[7];
    const float* W1   = (const float*)d_in[8];
    const float* b1   = (const float*)d_in[9];
    const float* W2   = (const float*)d_in[10];
    const float* b2   = (const float*)d_in[11];
    float*       out  = (float*)d_out;

    if (ws_size >= (size_t)WS_FULL) {
        unsigned short* wsp    = (unsigned short*)d_ws;
        unsigned short* ctx_ws = (unsigned short*)((char*)d_ws + CTX_OFF_B);
        pack_weights_v2<<<(1060 * 64 + 255) / 256, 256, 0, stream>>>(WQ, WK, WV, W1, wsp);
        te_attn<<<B_, 512, 0, stream>>>(text, emb, bQ, bK, bV, b1, W2, wsp, ctx_ws, out);
        te_out<<<B_, 512, 0, stream>>>(ctx_ws, b2, out);
    } else {
        te_fused_fb<<<B_, 512, 0, stream>>>(text, emb, WQ, bQ, WK, bK, WV, bV,
                                            W1, b1, W2, b2, out);
    }
}

// Round 10
// 496.090 us; speedup vs baseline: 1.0900x; 1.0900x over previous
//
#include <hip/hip_runtime.h>
#include <hip/hip_bf16.h>

#define B_   2048
#define L_   64
#define H_   20
#define DK_  20
#define D_   300
#define HD_  400
#define F1_  200

typedef __attribute__((ext_vector_type(8))) short short8;
typedef __attribute__((ext_vector_type(4))) float f32x4;

// ---- workspace layout (kept EXACTLY at the R5/R6-proven requirement) ----
// [0, 819200)          : wqkv tiles, 800 * 1024 B
// [819200, 985600)     : W1 compact tiles: 130 * (512+128)*2 B  (kt0 full, kt1 compact)
// [1048576, +100 MB)   : ctx (bf16, row-major [b*64+tok][400])
#define WQKV_TILES   800             // hg(10) * kt(10) * nt(8)
#define W1C_OFF_U16  409600
#define W1_KT0_FR    130
#define CTX_OFF_B    1048576
#define CTX_BYTES    (2048L * 64 * 400 * 2)
#define WS_FULL      (CTX_OFF_B + CTX_BYTES)   // == 105906176, proven available

__device__ __forceinline__ float b2f(unsigned short u) {
    union { unsigned int i; float f; } v; v.i = ((unsigned int)u) << 16; return v.f;
}
__device__ __forceinline__ unsigned int f2b2(float a, float b) {
    union { __hip_bfloat162 h; unsigned int u; } cv;
    cv.h = __float22bfloat162_rn(make_float2(a, b));
    return cv.u;
}
__device__ __forceinline__ unsigned short f2b(float a) {
    union { __hip_bfloat16 h; unsigned short u; } cv;
    cv.h = __float2bfloat16(a);
    return cv.u;
}
__device__ __forceinline__ float rcpf(float x) { return __builtin_amdgcn_rcpf(x); }
__device__ __forceinline__ float rlane(float v, int l) {
    return __int_as_float(__builtin_amdgcn_readlane(__float_as_int(v), l));
}

// ==================== weight pre-pack v2 ====================
__global__ void pack_weights_v2(const float* __restrict__ WQ, const float* __restrict__ WK,
                                const float* __restrict__ WV, const float* __restrict__ W1,
                                unsigned short* __restrict__ wsp)
{
    const int tid  = blockIdx.x * 256 + threadIdx.x;
    const int frag = tid >> 6, l = tid & 63;
    if (frag >= 1060) return;
    const int octet = l >> 4, lo = l & 15;
    if (frag < WQKV_TILES) {
        const int hg = frag / 80, r = frag % 80, kt = r / 8, nt = r % 8;
        const int nl = nt * 16 + lo;
        const int sel = (nl < 120) ? nl / 40 : 0;
        const int within = nl % 40;
        const int h2 = within / 20, d = within % 20;
        const int col = (hg * 2 + h2) * 20 + d;
        const float* W = (sel == 0) ? WQ : (sel == 1) ? WK : WV;
        unsigned short v[8];
        #pragma unroll
        for (int j = 0; j < 8; ++j) {
            const int k = kt * 32 + octet * 8 + j;
            const float f = (nl < 120 && k < 300) ? W[k * 400 + col] : 0.f;
            v[j] = f2b(f);
        }
        unsigned short* dst = wsp + (long)frag * 512 + l * 8;
        *(ushort4*)(dst)     = make_ushort4(v[0], v[1], v[2], v[3]);
        *(ushort4*)(dst + 4) = make_ushort4(v[4], v[5], v[6], v[7]);
    } else if (frag < 800 + W1_KT0_FR) {
        const int f2 = frag - 800, hg = f2 / 13, nt = f2 % 13;
        const int n = nt * 16 + lo;
        unsigned short v[8];
        #pragma unroll
        for (int j = 0; j < 8; ++j) {
            const int kl = octet * 8 + j;
            const float f = (n < 200) ? W1[(hg * 40 + kl) * 200 + n] : 0.f;
            v[j] = f2b(f);
        }
        unsigned short* dst = wsp + W1C_OFF_U16 + (long)(hg * 13 + nt) * 640 + l * 8;
        *(ushort4*)(dst)     = make_ushort4(v[0], v[1], v[2], v[3]);
        *(ushort4*)(dst + 4) = make_ushort4(v[4], v[5], v[6], v[7]);
    } else {
        const int f2 = frag - 800 - W1_KT0_FR, hg = f2 / 13, nt = f2 % 13;
        if (l < 16) {
            const int n = nt * 16 + l;
            unsigned short v[8];
            #pragma unroll
            for (int j = 0; j < 8; ++j) {
                const float f = (n < 200) ? W1[(hg * 40 + 32 + j) * 200 + n] : 0.f;
                v[j] = f2b(f);
            }
            unsigned short* dst = wsp + W1C_OFF_U16 + (long)(hg * 13 + nt) * 640 + 512 + l * 8;
            *(ushort4*)(dst)     = make_ushort4(v[0], v[1], v[2], v[3]);
            *(ushort4*)(dst + 4) = make_ushort4(v[4], v[5], v[6], v[7]);
        }
    }
}

// ==================== te_attn helpers (reference-to-array params: no decay) ====================
template<int S>
__device__ __forceinline__ void a_step(int hg0, int w, int l, bool act, int selbase,
                                       const unsigned short* xp,
                                       const unsigned short* __restrict__ wsp,
                                       const float* bq, f32x4 (&slab)[2][4])
{
    #pragma unroll
    for (int s = 0; s < S; ++s) {
        const float bv = act ? bq[selbase + (hg0 + s) * 40] : 0.f;
        #pragma unroll
        for (int mt = 0; mt < 4; ++mt) slab[s][mt] = (f32x4){bv, bv, bv, bv};
    }
    for (int kt = 0; kt < 10; ++kt) {
        short8 a[4];
        #pragma unroll
        for (int mt = 0; mt < 4; ++mt)
            a[mt] = *(const short8*)(xp + ((mt * 10 + kt) * 64 + l) * 8);
        #pragma unroll
        for (int s = 0; s < S; ++s) {
            const short8 bf = *(const short8*)(wsp + ((long)((hg0 + s) * 80 + kt * 8 + w) * 512) + l * 8);
            #pragma unroll
            for (int mt = 0; mt < 4; ++mt)
                slab[s][mt] = __builtin_amdgcn_mfma_f32_16x16x32_bf16(a[mt], bf, slab[s][mt], 0, 0, 0);
        }
    }
}

// incremental pooling-GEMM accumulation over one hg's ctx slice (stage, row-major [tok][40])
__device__ __forceinline__ void d_accum(int hg, int l, int w, int quad,
                                        const unsigned short* stage,
                                        const unsigned short* __restrict__ wsp,
                                        f32x4 (&accD)[2][4])
{
    short8 a0[4], a1[4];
    const short8 zz = {0, 0, 0, 0, 0, 0, 0, 0};
    #pragma unroll
    for (int mt = 0; mt < 4; ++mt) {
        const int tok = mt * 16 + (l & 15);
        a0[mt] = *(const short8*)(stage + tok * 40 + quad * 8);
        a1[mt] = (quad == 0) ? *(const short8*)(stage + tok * 40 + 32) : zz;
    }
    {
        const unsigned short* base = wsp + W1C_OFF_U16 + (long)(hg * 13 + w) * 640;
        const short8 wb0 = *(const short8*)(base + l * 8);
        const short8 wb1 = *(const short8*)(base + 512 + (l & 15) * 8);
        #pragma unroll
        for (int mt = 0; mt < 4; ++mt) {
            accD[0][mt] = __builtin_amdgcn_mfma_f32_16x16x32_bf16(a0[mt], wb0, accD[0][mt], 0, 0, 0);
            accD[0][mt] = __builtin_amdgcn_mfma_f32_16x16x32_bf16(a1[mt], wb1, accD[0][mt], 0, 0, 0);
        }
    }
    if (w + 8 < 13) {
        const unsigned short* base = wsp + W1C_OFF_U16 + (long)(hg * 13 + w + 8) * 640;
        const short8 wb0 = *(const short8*)(base + l * 8);
        const short8 wb1 = *(const short8*)(base + 512 + (l & 15) * 8);
        #pragma unroll
        for (int mt = 0; mt < 4; ++mt) {
            accD[1][mt] = __builtin_amdgcn_mfma_f32_16x16x32_bf16(a0[mt], wb0, accD[1][mt], 0, 0, 0);
            accD[1][mt] = __builtin_amdgcn_mfma_f32_16x16x32_bf16(a1[mt], wb1, accD[1][mt], 0, 0, 0);
        }
    }
}

// per-head-group attention body (5 barriers); drains prev hg's ctx (copy + D-accum)
__device__ __forceinline__ void attn_hg_body(
    int hg, const f32x4 (&sl)[4], int b, int t, int l, int w,
    bool act, int sel, int baseQK, int baseV, int quad,
    unsigned short* trans, unsigned short* vBs, unsigned short* stage,
    float* rsum_s, unsigned short* __restrict__ ctx_ws,
    const unsigned short* __restrict__ wsp, f32x4 (&accD)[2][4])
{
    if (hg > 0) {
        for (int u = t; u < 640; u += 512) {
            const int row = u / 10, c4 = u - row * 10;
            const ushort4 v = *(const ushort4*)(stage + row * 40 + c4 * 4);
            *(ushort4*)(ctx_ws + ((long)(b * 64 + row)) * 400 + (hg - 1) * 40 + c4 * 4) = v;
        }
        d_accum(hg - 1, l, w, quad, stage, wsp, accD);
    }
    if (act) {
        const unsigned int u01a = f2b2(sl[0][0], sl[0][1]), u23a = f2b2(sl[0][2], sl[0][3]);
        const unsigned int u01b = f2b2(sl[1][0], sl[1][1]), u23b = f2b2(sl[1][2], sl[1][3]);
        const unsigned int u01c = f2b2(sl[2][0], sl[2][1]), u23c = f2b2(sl[2][2], sl[2][3]);
        const unsigned int u01d = f2b2(sl[3][0], sl[3][1]), u23d = f2b2(sl[3][2], sl[3][3]);
        const unsigned int p01[4] = {u01a, u01b, u01c, u01d};
        const unsigned int p23[4] = {u23a, u23b, u23c, u23d};
        if (sel < 2) {
            #pragma unroll
            for (int mt = 0; mt < 4; ++mt) {
                const int a0 = baseQK + mt * 512;
                trans[a0]      = (unsigned short)p01[mt];
                trans[a0 + 8]  = (unsigned short)(p01[mt] >> 16);
                trans[a0 + 16] = (unsigned short)p23[mt];
                trans[a0 + 24] = (unsigned short)(p23[mt] >> 16);
            }
        } else {
            #pragma unroll
            for (int mt = 0; mt < 4; ++mt) {
                const int bm = baseV + (mt >> 1) * 1024 + (mt & 1) * 256;
                #pragma unroll
                for (int ii = 0; ii < 4; ++ii) {
                    const int tq = quad * 4 + ii;
                    const unsigned int uu = (ii < 2) ? p01[mt] : p23[mt];
                    vBs[bm + (tq >> 3) * 128 + (tq & 7)] =
                        (unsigned short)((ii & 1) ? (uu >> 16) : uu);
                }
            }
        }
    }
    __syncthreads();                                   // B1

    const int h = w >> 2, jt = w & 3;
    f32x4 accS[4];
    #pragma unroll
    for (int mt = 0; mt < 4; ++mt) accS[mt] = (f32x4){0.f, 0.f, 0.f, 0.f};
    {
        short8 qa[4];
        #pragma unroll
        for (int mt = 0; mt < 4; ++mt)
            qa[mt] = *(const short8*)(trans + ((h * 4 + mt) * 64 + l) * 8);
        const short8 kb = *(const short8*)(trans + 4096 + ((h * 4 + jt) * 64 + l) * 8);
        #pragma unroll
        for (int mt = 0; mt < 4; ++mt)
            accS[mt] = __builtin_amdgcn_mfma_f32_16x16x32_bf16(qa[mt], kb, accS[mt], 0, 0, 0);
    }
    __syncthreads();                                   // B2
    {
        const int jtok = jt * 16 + (l & 15);
        const int ktp = jtok >> 5;
        #pragma unroll
        for (int mt = 0; mt < 4; ++mt) {
            const float e0 = __expf(accS[mt][0] * 0.22360679774997896f);
            const float e1 = __expf(accS[mt][1] * 0.22360679774997896f);
            const float e2 = __expf(accS[mt][2] * 0.22360679774997896f);
            const float e3 = __expf(accS[mt][3] * 0.22360679774997896f);
            const unsigned int u01 = f2b2(e0, e1), u23 = f2b2(e2, e3);
            const int a0 = (((h * 4 + mt) * 2 + ktp) * 64 + quad * 4 + ((jtok & 31) >> 3) * 16) * 8 + (jtok & 7);
            trans[a0]      = (unsigned short)u01;
            trans[a0 + 8]  = (unsigned short)(u01 >> 16);
            trans[a0 + 16] = (unsigned short)u23;
            trans[a0 + 24] = (unsigned short)(u23 >> 16);
        }
    }
    __syncthreads();                                   // B3

    const int dnt = (w >> 1) & 1, mh = w & 1;
    f32x4 accC[2];
    accC[0] = (f32x4){0.f, 0.f, 0.f, 0.f};
    accC[1] = (f32x4){0.f, 0.f, 0.f, 0.f};
    #pragma unroll
    for (int ktc = 0; ktc < 2; ++ktc) {
        const short8 vb = *(const short8*)(vBs + (((h * 2 + ktc) * 2 + dnt) * 64 + l) * 8);
        #pragma unroll
        for (int mi = 0; mi < 2; ++mi) {
            const int mt = mh * 2 + mi;
            const short8 pa = *(const short8*)(trans + (((h * 4 + mt) * 2 + ktc) * 64 + l) * 8);
            accC[mi] = __builtin_amdgcn_mfma_f32_16x16x32_bf16(pa, vb, accC[mi], 0, 0, 0);
        }
    }
    if (dnt == 1 && (l & 15) == 4) {
        #pragma unroll
        for (int mi = 0; mi < 2; ++mi)
            #pragma unroll
            for (int ii = 0; ii < 4; ++ii)
                rsum_s[h * 64 + (mh * 2 + mi) * 16 + quad * 4 + ii] = accC[mi][ii];
    }
    __syncthreads();                                   // B4
    if (hg < 9) {
        unsigned int* tz = (unsigned int*)trans;
        for (int i = t; i < 4096; i += 512) tz[i] = 0u;
    }
    {
        const int dloc = dnt * 16 + (l & 15);
        if (dloc < 20) {
            const int cl = h * 20 + dloc;
            #pragma unroll
            for (int mi = 0; mi < 2; ++mi) {
                const int mt = mh * 2 + mi;
                float vv[4];
                #pragma unroll
                for (int ii = 0; ii < 4; ++ii) {
                    const int tok = mt * 16 + quad * 4 + ii;
                    vv[ii] = accC[mi][ii] * rcpf(rsum_s[h * 64 + tok] + 1e-8f);
                }
                const unsigned int u01 = f2b2(vv[0], vv[1]), u23 = f2b2(vv[2], vv[3]);
                const int base = (mt * 16 + quad * 4) * 40 + cl;
                stage[base]       = (unsigned short)u01;
                stage[base + 40]  = (unsigned short)(u01 >> 16);
                stage[base + 80]  = (unsigned short)u23;
                stage[base + 120] = (unsigned short)(u23 >> 16);
            }
        }
    }
    __syncthreads();                                   // B5
}

// ==================== kernel 1: attention + fused pooling-GEMM ====================
// waves_per_eu(4,4) is the ONLY waves-per-EU spec (no launch_bounds min-waves arg):
// budget = 512/4 = 128 VGPRs, and the allocator must not spill to chase 8 waves/EU.
__global__ __launch_bounds__(512) __attribute__((amdgpu_waves_per_eu(4, 4)))
void te_attn(const int* __restrict__ text,
             const float* __restrict__ emb,
             const float* __restrict__ bQ, const float* __restrict__ bK,
             const float* __restrict__ bV,
             const float* __restrict__ b1, const float* __restrict__ W2,
             const unsigned short* __restrict__ wsp,
             unsigned short* __restrict__ ctx_ws,
             float* __restrict__ logit_out)       // = d_out; logits at [b*400 + tok]
{
    __shared__ unsigned short x_pack[4 * 10 * 64 * 8];   // 40960 B
    __shared__ unsigned short trans[8192];               // 16384 B
    __shared__ unsigned short vB[4096];                  // 8192 B
    __shared__ unsigned short ctx_stage[64 * 40];        // 5120 B
    __shared__ float bqkv_s[1200];
    __shared__ float b1_s[208], w2_s[208];
    __shared__ float rsum_s[128];
    __shared__ float aacc_s[64];
    __shared__ int   text_s[64];

    const int b = blockIdx.x;
    const int t = threadIdx.x;
    const int l = t & 63;
    const int w = t >> 6;
    const int quad = l >> 4;

    {
        unsigned int* xz = (unsigned int*)x_pack;
        for (int i = t; i < 10240; i += 512) xz[i] = 0u;
        unsigned int* tz = (unsigned int*)trans;
        for (int i = t; i < 4096; i += 512) tz[i] = 0u;
        unsigned int* vz = (unsigned int*)vB;
        for (int i = t; i < 2048; i += 512) {
            const int tile = i >> 8;
            const int lane_v = (i & 255) >> 2;
            vz[i] = ((tile & 1) == 1 && (lane_v & 15) == 4) ? 0x3F803F80u : 0u;
        }
        for (int i = t; i < 1200; i += 512)
            bqkv_s[i] = (i < 400) ? bQ[i] : (i < 800) ? bK[i - 400] : bV[i - 800];
        if (t < 208) { b1_s[t] = (t < 200) ? b1[t] : 0.f; w2_s[t] = (t < 200) ? W2[t] : 0.f; }
        if (t >= 208 && t < 272) aacc_s[t - 208] = 0.f;
        if (t >= 272 && t < 336) text_s[t - 272] = text[b * L_ + (t - 272)];
    }
    __syncthreads();

    for (int u = t; u < 64 * 75; u += 512) {
        const int r = u / 75, c4 = u - r * 75, k = c4 * 4;
        const float4 f = *(const float4*)(emb + (long)text_s[r] * D_ + k);
        const int mt = r >> 4, kt = k >> 5;
        const int ld = (r & 15) + ((k & 31) >> 3) * 16;
        const unsigned int u01 = f2b2(f.x, f.y), u23 = f2b2(f.z, f.w);
        *(uint2*)(x_pack + ((mt * 10 + kt) * 64 + ld) * 8 + (k & 7)) = make_uint2(u01, u23);
    }
    __syncthreads();

    const int nl = w * 16 + (l & 15);
    const bool act = nl < 120;
    int sel = 0, h2 = 0, d = 0;
    if (act) { sel = nl / 40; const int within = nl % 40; h2 = within / 20; d = within % 20; }
    const int baseQK = h2 * 2048 + (quad * 4 + (d >> 3) * 16) * 8 + (d & 7) + ((sel == 1) ? 4096 : 0);
    const int baseV  = h2 * 2048 + (d >> 4) * 512 + (d & 15) * 8;
    const int selbase = sel * 400 + h2 * 20 + d;

    f32x4 accD[2][4];
    #pragma unroll
    for (int g = 0; g < 2; ++g)
        #pragma unroll
        for (int mt = 0; mt < 4; ++mt) accD[g][mt] = (f32x4){0.f, 0.f, 0.f, 0.f};

    // 5 A-steps of 2 head-groups each (slab = 32 VGPRs)
    f32x4 slab[2][4];
    #pragma unroll 1
    for (int hp = 0; hp < 5; ++hp) {
        const int hg0 = hp * 2;
        a_step<2>(hg0, w, l, act, selbase, x_pack, wsp, bqkv_s, slab);
        attn_hg_body(hg0,     slab[0], b, t, l, w, act, sel, baseQK, baseV, quad,
                     trans, vB, ctx_stage, rsum_s, ctx_ws, wsp, accD);
        attn_hg_body(hg0 + 1, slab[1], b, t, l, w, act, sel, baseQK, baseV, quad,
                     trans, vB, ctx_stage, rsum_s, ctx_ws, wsp, accD);
    }

    // tail: drain hg=9 (copy + D-accum), then logits
    for (int u = t; u < 640; u += 512) {
        const int row = u / 10, c4 = u - row * 10;
        const ushort4 v = *(const ushort4*)(ctx_stage + row * 40 + c4 * 4);
        *(ushort4*)(ctx_ws + ((long)(b * 64 + row)) * 400 + 9 * 40 + c4 * 4) = v;
    }
    d_accum(9, l, w, quad, ctx_stage, wsp, accD);

    // logit epilogue: tanh(e)·W2, reduce over cols -> aacc_s[tok]
    #pragma unroll
    for (int g = 0; g < 2; ++g) {
        const int ntv = (g == 0) ? w : w + 8;
        if (ntv < 13) {
            const int colb = ntv * 16 + (l & 15);      // cols>=200 have b1=w2=0 -> contribute 0
            const float b1v = b1_s[colb], w2v = w2_s[colb];
            #pragma unroll
            for (int mt = 0; mt < 4; ++mt) {
                float part[4];
                #pragma unroll
                for (int ii = 0; ii < 4; ++ii) {
                    const float x = accD[g][mt][ii] + b1v;
                    const float ex = __expf(2.f * x);
                    part[ii] = (1.f - 2.f * rcpf(ex + 1.f)) * w2v;
                }
                #pragma unroll
                for (int ii = 0; ii < 4; ++ii) {
                    float v = part[ii];
                    v += __shfl_xor(v, 1, 64); v += __shfl_xor(v, 2, 64);
                    v += __shfl_xor(v, 4, 64); v += __shfl_xor(v, 8, 64);
                    if ((l & 15) == 0)
                        atomicAdd(&aacc_s[mt * 16 + quad * 4 + ii], v);
                }
            }
        }
    }
    __syncthreads();
    if (t < 64)
        logit_out[(long)b * HD_ + t] = aacc_s[t];
}

// ==================== kernel 2: output (alpha + weighted sum) ====================
__global__ __launch_bounds__(512, 4)
void te_out(const unsigned short* __restrict__ ctx_ws,
            const float* __restrict__ b2,
            float* __restrict__ out)            // rows hold logits in [0,64) on entry
{
    __shared__ unsigned short ctx_l[64 * 400];  // 51200 B
    __shared__ float alpha_s[64];

    const int b = blockIdx.x;
    const int t = threadIdx.x;

    float av = 0.f;
    if (t < 64) av = __expf(out[(long)b * HD_ + t] + b2[0]);   // read logits FIRST

    for (int u = t; u < 3200; u += 512) {
        const int row = u / 50, c8 = u - row * 50;
        *(short8*)(ctx_l + row * 400 + c8 * 8) =
            *(const short8*)(ctx_ws + ((long)(b * 64 + row)) * 400 + c8 * 8);
    }
    if (t < 64) {
        float s = av;
        s += __shfl_xor(s, 32, 64); s += __shfl_xor(s, 16, 64);
        s += __shfl_xor(s, 8, 64);  s += __shfl_xor(s, 4, 64);
        s += __shfl_xor(s, 2, 64);  s += __shfl_xor(s, 1, 64);
        alpha_s[t] = av * rcpf(s + 1e-8f);
    }
    __syncthreads();

    if (t < HD_) {
        float a = 0.f;
        #pragma unroll 4
        for (int tok = 0; tok < 64; ++tok)
            a = fmaf(b2f(ctx_l[tok * 400 + t]), alpha_s[tok], a);
        out[(long)b * HD_ + t] = a;
    }
}

// ==================== last-resort fallback (no workspace) ====================
#define XS   324
#define CS   404
#define QS   21
#define SS   66

__global__ __launch_bounds__(512, 2)
void te_fused_fb(const int* __restrict__ text, const float* __restrict__ emb,
                 const float* __restrict__ WQ, const float* __restrict__ bQ,
                 const float* __restrict__ WK, const float* __restrict__ bK,
                 const float* __restrict__ WV, const float* __restrict__ bV,
                 const float* __restrict__ W1, const float* __restrict__ b1,
                 const float* __restrict__ W2, const float* __restrict__ b2,
                 float* __restrict__ out)
{
    __shared__ int            text_s[L_];
    __shared__ unsigned short x_s[L_ * XS];
    __shared__ unsigned short ctx_s[L_ * CS];
    __shared__ float          qkv_s[3 * 2 * L_ * QS];
    __shared__ unsigned short sc_s[2 * L_ * SS];
    __shared__ float          aacc_s[L_], alpha_s[L_];
    __shared__ float          inv_asum_s;

    const int b = blockIdx.x, t = threadIdx.x, lane = t & 63, wv = t >> 6;
    if (t < 64) text_s[t] = text[b * L_ + t];
    if (t >= 64 && t < 128) aacc_s[t - 64] = 0.f;
    __syncthreads();
    for (int u = t; u < L_ * 75; u += 512) {
        int l = u / 75, c4 = u - l * 75;
        const float4 f = *(const float4*)(emb + (long)text_s[l] * D_ + c4 * 4);
        ushort4 o; o.x = f2b(f.x); o.y = f2b(f.y); o.z = f2b(f.z); o.w = f2b(f.w);
        *(ushort4*)(x_s + l * XS + c4 * 4) = o;
    }
    __syncthreads();
    for (int hp = 0; hp < H_ / 2; ++hp) {
        const int h0 = hp * 2;
        if (t < 480) {
            const int rt = t & 15, ct = t >> 4, r0 = rt * 4, qc = ct * 4;
            const int sel = qc / 40, rem = qc - sel * 40, hh = rem / 20, cc = rem - hh * 20;
            const float* W = (sel == 0) ? WQ : (sel == 1) ? WK : WV;
            const float* bias = (sel == 0) ? bQ : (sel == 1) ? bK : bV;
            const int col0 = (h0 + hh) * 20 + cc;
            float acc[4][4];
            #pragma unroll
            for (int j = 0; j < 4; ++j) {
                const float bj = bias[col0 + j];
                acc[0][j] = bj; acc[1][j] = bj; acc[2][j] = bj; acc[3][j] = bj;
            }
            const float* Wp = W + col0;
            for (int c4 = 0; c4 < 75; ++c4) {
                const int d0 = c4 * 4;
                float xv[4][4]; float4 wvv[4];
                #pragma unroll
                for (int i = 0; i < 4; ++i) {
                    ushort4 xu = *(const ushort4*)(x_s + (r0 + i) * XS + d0);
                    xv[i][0] = b2f(xu.x); xv[i][1] = b2f(xu.y);
                    xv[i][2] = b2f(xu.z); xv[i][3] = b2f(xu.w);
                }
                #pragma unroll
                for (int dd = 0; dd < 4; ++dd)
                    wvv[dd] = *(const float4*)(Wp + (long)(d0 + dd) * HD_);
                #pragma unroll
                for (int dd = 0; dd < 4; ++dd)
                    #pragma unroll
                    for (int i = 0; i < 4; ++i) {
                        acc[i][0] = fmaf(xv[i][dd], wvv[dd].x, acc[i][0]);
                        acc[i][1] = fmaf(xv[i][dd], wvv[dd].y, acc[i][1]);
                        acc[i][2] = fmaf(xv[i][dd], wvv[dd].z, acc[i][2]);
                        acc[i][3] = fmaf(xv[i][dd], wvv[dd].w, acc[i][3]);
                    }
            }
            #pragma unroll
            for (int i = 0; i < 4; ++i)
                #pragma unroll
                for (int j = 0; j < 4; ++j)
                    qkv_s[((sel * 2 + hh) * L_ + r0 + i) * QS + cc + j] = acc[i][j];
        }
        __syncthreads();
        {
            const int j = lane, ig = wv & 3, hh = wv >> 2;
            float qreg[20], kreg[20];
            const float* qrow = &qkv_s[((0 * 2 + hh) * L_ + j) * QS];
            const float* krow = &qkv_s[((1 * 2 + hh) * L_ + j) * QS];
            #pragma unroll
            for (int dd = 0; dd < 20; ++dd) { qreg[dd] = qrow[dd]; kreg[dd] = krow[dd]; }
            for (int ii = 0; ii < 16; ++ii) {
                const int i = ig * 16 + ii;
                float s = 0.f;
                #pragma unroll
                for (int dd = 0; dd < 20; ++dd) s = fmaf(rlane(qreg[dd], i), kreg[dd], s);
                sc_s[(hh * L_ + i) * SS + j] = f2b(__expf(s * 0.22360679774997896f));
            }
        }
        __syncthreads();
        {
            const int i = lane, dg = wv, head = dg >> 2, dv0 = (dg & 3) * 5;
            float vreg[5];
            #pragma unroll
            for (int m = 0; m < 5; ++m)
                vreg[m] = qkv_s[((2 * 2 + head) * L_ + i) * QS + dv0 + m];
            float acc[5] = {0.f, 0.f, 0.f, 0.f, 0.f};
            float rsum = 0.f;
            const unsigned short* prow = &sc_s[(head * L_ + i) * SS];
            for (int jj = 0; jj < 64; ++jj) {
                const float p = b2f(prow[jj]);
                rsum += p;
                #pragma unroll
                for (int m = 0; m < 5; ++m) acc[m] = fmaf(p, rlane(vreg[m], jj), acc[m]);
            }
            const float inv = 1.f / (rsum + 1e-8f);
            const int col0 = (h0 + head) * 20 + dv0;
            #pragma unroll
            for (int m = 0; m < 5; ++m) ctx_s[i * CS + col0 + m] = f2b(acc[m] * inv);
        }
        __syncthreads();
    }
    for (int tau = t; tau < 800; tau += 512) {
        const int rt = tau & 15, cm = tau >> 4, r0 = rt * 4, m0 = cm * 4;
        float acc[4][4];
        #pragma unroll
        for (int j = 0; j < 4; ++j) {
            const float bj = b1[m0 + j];
            acc[0][j] = bj; acc[1][j] = bj; acc[2][j] = bj; acc[3][j] = bj;
        }
        for (int c4 = 0; c4 < 100; ++c4) {
            const int c0 = c4 * 4;
            float cv[4][4]; float4 wv1[4];
            #pragma unroll
            for (int i = 0; i < 4; ++i) {
                ushort4 cu = *(const ushort4*)(ctx_s + (r0 + i) * CS + c0);
                cv[i][0] = b2f(cu.x); cv[i][1] = b2f(cu.y);
                cv[i][2] = b2f(cu.z); cv[i][3] = b2f(cu.w);
            }
            #pragma unroll
            for (int dd = 0; dd < 4; ++dd)
                wv1[dd] = *(const float4*)(W1 + (long)(c0 + dd) * F1_ + m0);
            #pragma unroll
            for (int dd = 0; dd < 4; ++dd)
                #pragma unroll
                for (int i = 0; i < 4; ++i) {
                    acc[i][0] = fmaf(cv[i][dd], wv1[dd].x, acc[i][0]);
                    acc[i][1] = fmaf(cv[i][dd], wv1[dd].y, acc[i][1]);
                    acc[i][2] = fmaf(cv[i][dd], wv1[dd].z, acc[i][2]);
                    acc[i][3] = fmaf(cv[i][dd], wv1[dd].w, acc[i][3]);
                }
        }
        float w2l[4];
        #pragma unroll
        for (int j = 0; j < 4; ++j) w2l[j] = W2[m0 + j];
        #pragma unroll
        for (int i = 0; i < 4; ++i) {
            float ap = 0.f;
            #pragma unroll
            for (int j = 0; j < 4; ++j) ap += tanhf(acc[i][j]) * w2l[j];
            atomicAdd(&aacc_s[r0 + i], ap);
        }
    }
    __syncthreads();
    if (t < 64) {
        const float a = __expf(aacc_s[t] + b2[0]);
        alpha_s[t] = a;
        float s = a;
        s += __shfl_xor(s, 32, 64); s += __shfl_xor(s, 16, 64);
        s += __shfl_xor(s, 8, 64);  s += __shfl_xor(s, 4, 64);
        s += __shfl_xor(s, 2, 64);  s += __shfl_xor(s, 1, 64);
        if (t == 0) inv_asum_s = 1.f / (s + 1e-8f);
    }
    __syncthreads();
    if (t < HD_) {
        float a = 0.f;
        for (int l2 = 0; l2 < 64; ++l2)
            a = fmaf(b2f(ctx_s[l2 * CS + t]), alpha_s[l2], a);
        out[(long)b * HD_ + t] = a * inv_asum_s;
    }
}

extern "C" void kernel_launch(void* const* d_in, const int* in_sizes, int n_in,
                              void* d_out, int out_size, void* d_ws, size_t ws_size,
                              hipStream_t stream) {
    const int*   text = (const int*)d_in[0];
    const float* emb  = (const float*)d_in[1];
    const float* WQ   = (const float*)d_in[2];
    const float* bQ   = (const float*)d_in[3];
    const float* WK   = (const float*)d_in[4];
    const float* bK   = (const float*)d_in[5];
    const float* WV   = (const float*)d_in[6];
    const float* bV   = (const float*)d_in[7];
    const float* W1   = (const float*)d_in[8];
    const float* b1   = (const float*)d_in[9];
    const float* W2   = (const float*)d_in[10];
    const float* b2   = (const float*)d_in[11];
    float*       out  = (float*)d_out;

    if (ws_size >= (size_t)WS_FULL) {
        unsigned short* wsp    = (unsigned short*)d_ws;
        unsigned short* ctx_ws = (unsigned short*)((char*)d_ws + CTX_OFF_B);
        pack_weights_v2<<<(1060 * 64 + 255) / 256, 256, 0, stream>>>(WQ, WK, WV, W1, wsp);
        te_attn<<<B_, 512, 0, stream>>>(text, emb, bQ, bK, bV, b1, W2, wsp, ctx_ws, out);
        te_out<<<B_, 512, 0, stream>>>(ctx_ws, b2, out);
    } else {
        te_fused_fb<<<B_, 512, 0, stream>>>(text, emb, WQ, bQ, WK, bK, WV, bV,
                                            W1, b1, W2, b2, out);
    }
}